// Round 1
// 93.067 us; speedup vs baseline: 1.0792x; 1.0792x over previous
//
#include <hip/hip_runtime.h>
#include <hip/hip_bf16.h>
#include <stdint.h>

// bf16 MFMA operand: 8 bf16 in 4 VGPRs
typedef short bf16x8 __attribute__((ext_vector_type(8)));
typedef float f32x16 __attribute__((ext_vector_type(16)));

#define NROWS 8192
#define CDIM  128
#define TEMP  0.07f
// log2(e)/0.07
#define C1F   20.6099291555566248f

// ws layout offsets (bytes) past Xb (2 MB)
#define OFF_S    0
#define OFF_G    32768
#define OFF_HIST (32768 + 2048)
#define OFF_SUM  (32768 + 2048 + 16)
#define OFF_TKT  (32768 + 2048 + 16 + 4)
#define ZBYTES   (32768 + 2048 + 16 + 4 + 4)
#define ZWORDS   (ZBYTES / 4)   // 8710
// per-block G partials (256 blocks x 4 labels x 128 ch) + label counts
#define OFF_GPART (ZBYTES + 8)                  // 34848: 16B aligned
#define OFF_CPART (OFF_GPART + 256 * 512 * 4)   // 559136: 16B aligned

__device__ __forceinline__ float bf2f(unsigned short u) {
  union { unsigned int i; float f; } x; x.i = ((unsigned int)u) << 16; return x.f;
}
__device__ __forceinline__ unsigned short f2bf(float f) {
  union { float f; unsigned int i; } x; x.f = f;
  unsigned int r = x.i + 0x7fffu + ((x.i >> 16) & 1u);  // RNE
  return (unsigned short)(r >> 16);
}
__device__ __forceinline__ float fexp2(float x) {
#if __has_builtin(__builtin_amdgcn_exp2f)
  return __builtin_amdgcn_exp2f(x);
#else
  return exp2f(x);
#endif
}

// ---------------------------------------------------------------------------
// K1: pack features -> X bf16 [8192][128], zero stats region, AND compute
// per-block label-group sums (from f32, data already in LDS) + label counts.
// Gpart/Cpart are pure writes (no zero-init, no atomics). row n = g*1024+hw.
// ---------------------------------------------------------------------------
__global__ __launch_bounds__(256) void k_pack(const float* __restrict__ F,
                                              const int* __restrict__ labels,
                                              unsigned short* __restrict__ Xb,
                                              float* __restrict__ zbase,
                                              float* __restrict__ Gpart,
                                              int* __restrict__ Cpart) {
  const int tid = threadIdx.x;
  // fold-in: zero S/G/hist/sumLoss/ticket (34840 B) across first 35 blocks
  {
    int idx = blockIdx.x * 256 + tid;
    if (idx < ZWORDS) zbase[idx] = 0.0f;
  }
  __shared__ float lds[128 * 33];
  __shared__ int   slab[32];
  __shared__ float gred[4][128];
  const int g   = blockIdx.x >> 5;          // 0..7
  const int hw0 = (blockIdx.x & 31) << 5;   // 0,32,..,992
  if (tid < 32) slab[tid] = labels[g * 1024 + hw0 + tid];
#pragma unroll
  for (int p = 0; p < 16; ++p) {
    int c  = p * 8 + (tid >> 5);
    int hw = hw0 + (tid & 31);
    lds[c * 33 + (tid & 31)] = F[(g * 128 + c) * 1024 + hw];
  }
  __syncthreads();
#pragma unroll
  for (int p = 0; p < 16; ++p) {
    int hwl = p * 2 + (tid >> 7);
    int c   = tid & 127;
    int row = g * 1024 + hw0 + hwl;
    Xb[row * 128 + c] = f2bf(lds[c * 33 + hwl]);
  }
  // ---- per-block G partials: thread = (channel c, row-half rh) ----
  const int c  = tid & 127;
  const int rh = tid >> 7;
  float a0 = 0.f, a1 = 0.f, a2 = 0.f, a3 = 0.f;
#pragma unroll
  for (int k = 0; k < 16; ++k) {
    int   hwl = rh * 16 + k;
    float v   = lds[c * 33 + hwl];
    int   lab = slab[hwl];
    a0 += (lab == 0) ? v : 0.f;
    a1 += (lab == 1) ? v : 0.f;
    a2 += (lab == 2) ? v : 0.f;
    a3 += (lab == 3) ? v : 0.f;
  }
  if (rh == 1) { gred[0][c] = a0; gred[1][c] = a1; gred[2][c] = a2; gred[3][c] = a3; }
  // label counts for this block's 32 rows
  if (tid >= 32 && tid < 36) {
    int j = tid - 32, cnt = 0;
#pragma unroll
    for (int k2 = 0; k2 < 32; ++k2) cnt += (slab[k2] == j);
    Cpart[blockIdx.x * 4 + j] = cnt;
  }
  __syncthreads();
  if (rh == 0) {
    float* gp = Gpart + blockIdx.x * 512;
    gp[0 * 128 + c] = a0 + gred[0][c];
    gp[1 * 128 + c] = a1 + gred[1][c];
    gp[2 * 128 + c] = a2 + gred[2][c];
    gp[3 * 128 + c] = a3 + gred[3][c];
  }
}

// ---------------------------------------------------------------------------
// K2: blocks 0..511  -> streaming X @ X^T with fused exp-sum.
//     blocks 512..519 -> reduce Gpart->G (+ Cpart->hist); these dispatch last
//     and run during the MFMA drain (free wall time).
// 64 rows per wave (two A-frag sets, 64 VGPRs resident): each ds_read_b128 of
// a B fragment now feeds TWO MFMAs, halving LDS-read traffic per FLOP (the
// previous binding resource: LDS 12.9us vs matrix 6.9us per CU). Grid 512 =
// exactly 2 blocks/CU resident (launch_bounds(256,2)), single round, no tail.
// LDS layout chunk-transposed + pad: int4 (kchunk c, col n) at c*33+n.
// ---------------------------------------------------------------------------
__global__ __launch_bounds__(256, 2) void k_main(const unsigned short* __restrict__ Xb,
                                                 float* __restrict__ S,
                                                 float* __restrict__ G,
                                                 int* __restrict__ hist,
                                                 const float* __restrict__ Gpart,
                                                 const int* __restrict__ Cpart) {
  __shared__ int4 ldsB[2][2][16 * 33];
  const int bid  = blockIdx.x;
  const int tid  = threadIdx.x;
  const int lane = tid & 63;

  if (bid >= 512) {
    // ---- Gpart/Cpart reduction path (8 tiny blocks) ----
    const int rb = bid - 512;           // 0..7, owns 64 of the 512 G slots
    const int l  = tid & 63;
    const int w  = tid >> 6;            // wave sums partial-blocks w*64..w*64+63
    const float* gp = Gpart + (w * 64) * 512 + rb * 64 + l;
    float s = 0.f;
#pragma unroll 8
    for (int k = 0; k < 64; ++k) s += gp[k * 512];
    __shared__ float red[4][64];
    red[w][l] = s;
    __syncthreads();
    if (w == 0) G[rb * 64 + l] = red[0][l] + red[1][l] + red[2][l] + red[3][l];
    if (rb == 0) {
      int4 c4 = ((const int4*)Cpart)[tid];   // tid 0..255 covers all 256 blocks
      for (int mm = 1; mm < 64; mm <<= 1) {
        c4.x += __shfl_xor(c4.x, mm, 64);
        c4.y += __shfl_xor(c4.y, mm, 64);
        c4.z += __shfl_xor(c4.z, mm, 64);
        c4.w += __shfl_xor(c4.w, mm, 64);
      }
      __shared__ int hred[4][4];
      if (l == 0) { hred[w][0] = c4.x; hred[w][1] = c4.y; hred[w][2] = c4.z; hred[w][3] = c4.w; }
      __syncthreads();
      if (tid < 4) hist[tid] = hred[0][tid] + hred[1][tid] + hred[2][tid] + hred[3][tid];
    }
    return;
  }

  // ---- main MFMA path ----
  const int wave     = tid >> 6;
  const int rowBlock = bid >> 4;            // 0..31
  const int split    = bid & 15;            // 0..15
  const int r0       = rowBlock * 256 + wave * 64;
  const int col0     = split * 512;
  const int m        = lane & 31;
  const int half     = lane >> 5;

  bf16x8 afrag0[8], afrag1[8];
#pragma unroll
  for (int s = 0; s < 8; ++s) {
    afrag0[s] = *(const bf16x8*)(Xb + (r0 + m) * CDIM + (half + 2 * s) * 8);
    afrag1[s] = *(const bf16x8*)(Xb + (r0 + 32 + m) * CDIM + (half + 2 * s) * 8);
  }

  float accS0[16], accS1[16];
#pragma unroll
  for (int r = 0; r < 16; ++r) { accS0[r] = 0.f; accS1[r] = 0.f; }

  // staging: col n_l (0..31) in group, chunk-pair bq (0..7); 64 cols/iteration
  const int n_l = tid >> 3;
  const int bq  = tid & 7;
  const unsigned short* src = Xb + (col0 + n_l) * CDIM + bq * 16;
  int4 v0 = *(const int4*)src;
  int4 v1 = *(const int4*)(src + 8);
  int4 v2 = *(const int4*)(src + 32 * CDIM);
  int4 v3 = *(const int4*)(src + 32 * CDIM + 8);
  ldsB[0][0][(2 * bq) * 33 + n_l]     = v0;
  ldsB[0][0][(2 * bq + 1) * 33 + n_l] = v1;
  ldsB[0][1][(2 * bq) * 33 + n_l]     = v2;
  ldsB[0][1][(2 * bq + 1) * 33 + n_l] = v3;
  src += 64 * CDIM;
  v0 = *(const int4*)src;
  v1 = *(const int4*)(src + 8);
  v2 = *(const int4*)(src + 32 * CDIM);
  v3 = *(const int4*)(src + 32 * CDIM + 8);

  for (int t = 0; t < 8; ++t) {
    __syncthreads();
    if (t < 7) {
      const int nb = (t + 1) & 1;
      ldsB[nb][0][(2 * bq) * 33 + n_l]     = v0;
      ldsB[nb][0][(2 * bq + 1) * 33 + n_l] = v1;
      ldsB[nb][1][(2 * bq) * 33 + n_l]     = v2;
      ldsB[nb][1][(2 * bq + 1) * 33 + n_l] = v3;
    }
    if (t < 6) {
      src += 64 * CDIM;
      v0 = *(const int4*)src;
      v1 = *(const int4*)(src + 8);
      v2 = *(const int4*)(src + 32 * CDIM);
      v3 = *(const int4*)(src + 32 * CDIM + 8);
    }
    const int cur = t & 1;
#pragma unroll
    for (int u = 0; u < 2; ++u) {
      f32x16 acc0, acc1;
#pragma unroll
      for (int r = 0; r < 16; ++r) { acc0[r] = 0.f; acc1[r] = 0.f; }
#pragma unroll
      for (int s = 0; s < 8; ++s) {
        bf16x8 bfrag = *(const bf16x8*)&ldsB[cur][u][(half + 2 * s) * 33 + m];
        acc0 = __builtin_amdgcn_mfma_f32_32x32x16_bf16(afrag0[s], bfrag, acc0, 0, 0, 0);
        acc1 = __builtin_amdgcn_mfma_f32_32x32x16_bf16(afrag1[s], bfrag, acc1, 0, 0, 0);
      }
      const int colbase = col0 + t * 64 + u * 32;
      // row-group 0 (rows r0..r0+31)
      if (r0 == colbase) {  // only tile that can contain the diagonal
        const int colg = colbase + m;
#pragma unroll
        for (int r = 0; r < 16; ++r) {
          int   row = r0 + (r & 3) + 8 * (r >> 2) + 4 * half;
          float arg = (row == colg) ? -1e30f : acc0[r] * C1F;
          accS0[r] += fexp2(arg);
        }
      } else {
#pragma unroll
        for (int r = 0; r < 16; ++r) accS0[r] += fexp2(acc0[r] * C1F);
      }
      // row-group 1 (rows r0+32..r0+63)
      if (r0 + 32 == colbase) {
        const int colg = colbase + m;
#pragma unroll
        for (int r = 0; r < 16; ++r) {
          int   row = r0 + 32 + (r & 3) + 8 * (r >> 2) + 4 * half;
          float arg = (row == colg) ? -1e30f : acc1[r] * C1F;
          accS1[r] += fexp2(arg);
        }
      } else {
#pragma unroll
        for (int r = 0; r < 16; ++r) accS1[r] += fexp2(acc1[r] * C1F);
      }
    }
  }

  // reduce over the 32 columns (lanes) of each half, one atomic per row
#pragma unroll
  for (int r = 0; r < 16; ++r) {
    float v = accS0[r];
    v += __shfl_xor(v, 1, 64);
    v += __shfl_xor(v, 2, 64);
    v += __shfl_xor(v, 4, 64);
    v += __shfl_xor(v, 8, 64);
    v += __shfl_xor(v, 16, 64);
    accS0[r] = v;
    float v2 = accS1[r];
    v2 += __shfl_xor(v2, 1, 64);
    v2 += __shfl_xor(v2, 2, 64);
    v2 += __shfl_xor(v2, 4, 64);
    v2 += __shfl_xor(v2, 8, 64);
    v2 += __shfl_xor(v2, 16, 64);
    accS1[r] = v2;
  }
  if (m == 0) {
#pragma unroll
    for (int r = 0; r < 16; ++r) {
      int rowoff = (r & 3) + 8 * (r >> 2) + 4 * half;
      atomicAdd(&S[r0 + rowoff], accS0[r]);
      atomicAdd(&S[r0 + 32 + rowoff], accS1[r]);
    }
  }
}

// ---------------------------------------------------------------------------
// K3: per-row loss + global reduction + completion-ticket final division.
// loss_i = log(S_i) - (dot(x_i,G_lab) - |x_i|^2) / (T * (hist[lab]-1))
// ---------------------------------------------------------------------------
__global__ __launch_bounds__(256) void k_loss(const unsigned short* __restrict__ Xb,
                                              const int* __restrict__ labels,
                                              const float* __restrict__ S,
                                              const float* __restrict__ G,
                                              const int* __restrict__ hist,
                                              float* __restrict__ sumLoss,
                                              int* __restrict__ ticket,
                                              float* __restrict__ out) {
  const int i   = blockIdx.x * 256 + threadIdx.x;
  const int lab = labels[i];
  const float* g = G + lab * 128;
  const unsigned short* x = Xb + i * CDIM;
  float dot = 0.f, nrm = 0.f;
#pragma unroll
  for (int cc = 0; cc < 16; ++cc) {
    int4 q = *(const int4*)(x + cc * 8);
    const unsigned int* qs = (const unsigned int*)&q;
#pragma unroll
    for (int j = 0; j < 4; ++j) {
      unsigned int u = qs[j];
      float lo = __uint_as_float(u << 16);
      float hi = __uint_as_float(u & 0xffff0000u);
      int   ci = cc * 8 + j * 2;
      dot += lo * g[ci] + hi * g[ci + 1];
      nrm += lo * lo + hi * hi;
    }
  }
  float Si   = S[i];
  float cnt  = (float)(hist[lab] - 1);
  float loss = logf(Si) - (dot - nrm) / (TEMP * cnt);
  float contrib = (lab != 0) ? loss : 0.f;
  for (int mm = 1; mm < 64; mm <<= 1) contrib += __shfl_xor(contrib, mm, 64);
  __shared__ float ws4[4];
  if ((threadIdx.x & 63) == 0) ws4[threadIdx.x >> 6] = contrib;
  __syncthreads();
  if (threadIdx.x == 0) {
    atomicAdd(sumLoss, ws4[0] + ws4[1] + ws4[2] + ws4[3]);
    __threadfence();
    int t = atomicAdd(ticket, 1);
    if (t == 31) {  // last block: all 32 sumLoss adds are ordered before this
      float total = atomicAdd(sumLoss, 0.0f);  // atomic read sees all adds
      out[0] = total / (float)(NROWS - hist[0]);
    }
  }
}

// ---------------------------------------------------------------------------
extern "C" void kernel_launch(void* const* d_in, const int* in_sizes, int n_in,
                              void* d_out, int out_size, void* d_ws, size_t ws_size,
                              hipStream_t stream) {
  const float* F      = (const float*)d_in[0];
  const int*   labels = (const int*)d_in[1];
  char* ws = (char*)d_ws;

  unsigned short* Xb      = (unsigned short*)ws;                 // 2 MB
  const size_t    offS    = (size_t)NROWS * CDIM * 2;            // 2097152
  float*          S       = (float*)(ws + offS + OFF_S);
  float*          G       = (float*)(ws + offS + OFF_G);
  int*            hist    = (int*)(ws + offS + OFF_HIST);
  float*          sumLoss = (float*)(ws + offS + OFF_SUM);
  int*            ticket  = (int*)(ws + offS + OFF_TKT);
  float*          Gpart   = (float*)(ws + offS + OFF_GPART);     // 512 KB
  int*            Cpart   = (int*)(ws + offS + OFF_CPART);       // 4 KB

  hipLaunchKernelGGL(k_pack, dim3(256), dim3(256), 0, stream, F, labels, Xb, S, Gpart, Cpart);
  hipLaunchKernelGGL(k_main, dim3(520), dim3(256), 0, stream, Xb, S, G, hist, Gpart, Cpart);
  hipLaunchKernelGGL(k_loss, dim3(32), dim3(256), 0, stream, Xb, labels, S, G, hist,
                     sumLoss, ticket, (float*)d_out);
}